// Round 13
// baseline (437.933 us; speedup 1.0000x reference)
//
#include <hip/hip_runtime.h>
#include <math.h>

#define T_SEQ  512
#define HID    128
#define G3     384   // 3*HID, gate order r,z,n
#define NL     4
#define CHUNK  8
#define NCHUNK (T_SEQ / CHUNK)   // 64

// workspace layout (float offsets)
#define GI_TOT   (NL * T_SEQ * G3)
#define SEQ_TOT  (NL * T_SEQ * HID)
#define FLAG_OFF (GI_TOT + SEQ_TOT)

__device__ __forceinline__ float fsig(float x) {
    float e = __expf(-x);
    return 1.0f / (1.0f + e);
}
__device__ __forceinline__ float ftanh(float x) {
    float ax = fabsf(x);
    float e = __expf(-2.0f * ax);
    float t = (1.0f - e) / (1.0f + e);
    return copysignf(t, x);
}
// lane-register broadcast: VALU v_readlane_b32, stays off the DS pipe
__device__ __forceinline__ float rdlane(float v, int k) {
    return __uint_as_float(__builtin_amdgcn_readlane(__float_as_uint(v), k));
}

// Handoff protocol (invalidate-free, stale-proof): writer = stores;
// __syncthreads (vmcnt drain -> L2); RELEASE agent flag store. Reader polls a
// RELAXED fetch_add(0) (RMW at the coherence point: no buffer_inv, no stale
// line). R13 refinement: the poll RMW (~900cy LLC) is ISSUED at step 2 and
// CHECKED at step 3 (latency hidden); next chunk's gi is prefetched into a
// second register set at step 4 (drain hidden under steps 4-5). Chunk heads
// carry no handshake cost in steady state.

// ---------------- init: reset handoff flags ----------------
__global__ void init_flags(int* fl) {
    int i = threadIdx.x;
    if (i < 8) fl[i * 16] = (i == 0) ? NCHUNK : 0;  // gi0 fully ready
}

// ---------------- layer-0 gi ----------------
__global__ void gi0_kernel(const float* __restrict__ x, const float* __restrict__ Wih0,
                           const float* __restrict__ bih, float* __restrict__ gi) {
    int t = blockIdx.x;
    int g = threadIdx.x;
    float x0 = x[t * 2048 + 1023];
    float x1 = x[t * 2048 + 1024 + 1023];
    gi[t * G3 + g] = bih[g] + Wih0[g * 2 + 0] * x0 + Wih0[g * 2 + 1] * x1;
}

// ---------------- persistent pipeline: 7 blocks x 256 threads ----------------
// bid 0,2,4,6 -> rec layer bid/2 ; bid 1,3,5 -> gi layer (bid+1)/2
__global__ __launch_bounds__(256, 1) void pipe_kernel(float* __restrict__ ws,
                                                      const float* __restrict__ WihR,
                                                      const float* __restrict__ bih,
                                                      const float* __restrict__ Whh,
                                                      const float* __restrict__ bhh) {
    __shared__ float smem[12288];  // gi: ps_big[8][4][384]; rec: psdb[2][1536] + aux@3072

    int bid  = blockIdx.x;
    int tid  = threadIdx.x;
    int lane = tid & 63;
    int q    = tid >> 6;         // wave = K-quarter
    int row0 = lane * 6;
    int* fl = (int*)(ws + FLAG_OFF);
    bool is_rec = (bid & 1) == 0;
    int  l      = is_rec ? (bid >> 1) : ((bid + 1) >> 1);

    if (is_rec) {
        // ---------------- rec role: layer l ----------------
        const float* W   = Whh + (size_t)l * G3 * HID;
        const float* gi  = ws + (size_t)l * T_SEQ * G3;
        float* seq_o     = ws + GI_TOT + (size_t)l * T_SEQ * HID;
        float* aux       = smem + 3072;            // [1024] chunk history
        int* in_flag     = &fl[l * 16];
        int* out_flag    = &fl[(4 + l) * 16];

        float w[6][32];
        const float* wbase = W + q * 32;
#pragma unroll
        for (int i = 0; i < 6; i++) {
            const float4* wr = reinterpret_cast<const float4*>(wbase + (size_t)(row0 + i) * HID);
#pragma unroll
            for (int c = 0; c < 8; c++) {
                float4 v = wr[c];
                w[i][c * 4 + 0] = v.x; w[i][c * 4 + 1] = v.y;
                w[i][c * 4 + 2] = v.z; w[i][c * 4 + 3] = v.w;
            }
        }

        int  m  = lane & 31;
        bool p2 = (lane < 32);
        int  j  = q * 32 + m;          // this wave's P2 output index
        const float* bb = bhh + (size_t)l * G3;
        float br = 0.f, bz = 0.f, bn = 0.f;
        if (p2) { br = bb[j]; bz = bb[HID + j]; bn = bb[2 * HID + j]; }

        float hs[32];                  // wave-uniform h slice (this wave's K-quarter)
#pragma unroll
        for (int k = 0; k < 32; k++) hs[k] = 0.f;
        float hprev = 0.f;
        float g_r[CHUNK], g_z[CHUNK], g_n[CHUNK];       // current chunk gi
        float n_r[CHUNK], n_z[CHUNK], n_n[CHUNK];       // prefetched next chunk gi
        int   fseen = 0;

        // prologue: wait chunk 0, stage its gi
        if (tid == 0) {
            while (__hip_atomic_fetch_add(in_flag, 0, __ATOMIC_RELAXED, __HIP_MEMORY_SCOPE_AGENT) < 1)
                __builtin_amdgcn_s_sleep(2);
        }
        __syncthreads();
        if (p2) {
            const float* gp = gi + j;
#pragma unroll
            for (int s = 0; s < CHUNK; s++) {
                g_r[s] = gp[s * G3];
                g_z[s] = gp[s * G3 + HID];
                g_n[s] = gp[s * G3 + 2 * HID];
            }
        }

        for (int c = 0; c < NCHUNK; c++) {
            int t0 = c * CHUNK;
            bool more = (c + 1 < NCHUNK);
#pragma unroll
            for (int s = 0; s < CHUNK; s++) {
                int t = t0 + s;
                float* psb = smem + (t & 1) * 1536;   // double-buffered partials
                // P1: matvec on wave-uniform hs (packed fp32, no LDS reads)
                float2 hs2[16];
#pragma unroll
                for (int k = 0; k < 16; k++) { hs2[k].x = hs[2 * k]; hs2[k].y = hs[2 * k + 1]; }
                float acc[6];
#pragma unroll
                for (int i = 0; i < 6; i++) {
                    const float2* w2 = reinterpret_cast<const float2*>(w[i]);
                    float2 s0 = {0.f, 0.f}, s1 = {0.f, 0.f};
#pragma unroll
                    for (int k = 0; k < 16; k += 2) {
                        s0 += w2[k]     * hs2[k];
                        s1 += w2[k + 1] * hs2[k + 1];
                    }
                    acc[i] = (s0.x + s0.y) + (s1.x + s1.y);
                }
#pragma unroll
                for (int i = 0; i < 6; i += 2) {
                    float2 p; p.x = acc[i]; p.y = acc[i + 1];
                    *reinterpret_cast<float2*>(&psb[q * G3 + row0 + i]) = p;
                }
                __syncthreads();   // the ONLY barrier per step
                // prefetch next chunk's gi right after the s==4 barrier
                // (spin for its flag concluded at s==3; barrier(4) ordered it)
                if (s == 4 && more && p2) {
                    const float* gp = gi + (size_t)(t0 + CHUNK) * G3 + j;
#pragma unroll
                    for (int u = 0; u < CHUNK; u++) {
                        n_r[u] = gp[u * G3];
                        n_z[u] = gp[u * G3 + HID];
                        n_n[u] = gp[u * G3 + 2 * HID];
                    }
                }
                // P2 (replicated per wave, lanes 0..31)
                float hn_bc = 0.f;
                if (p2) {
                    float ghr = (psb[j]         + psb[G3 + j])         + (psb[2*G3 + j]         + psb[3*G3 + j]);
                    float ghz = (psb[HID + j]   + psb[G3 + HID + j])   + (psb[2*G3 + HID + j]   + psb[3*G3 + HID + j]);
                    float ghn = (psb[2*HID + j] + psb[G3 + 2*HID + j]) + (psb[2*G3 + 2*HID + j] + psb[3*G3 + 2*HID + j]);
                    float r = fsig(g_r[s] + ghr + br);
                    float z = fsig(g_z[s] + ghz + bz);
                    float n = ftanh(g_n[s] + r * (ghn + bn));
                    float hn = (1.0f - z) * n + z * hprev;
                    hprev = hn;
                    aux[s * HID + j] = hn;
                    hn_bc = hn;
                }
                // flag poll: issue RMW at s==2 (latency hides under step 3),
                // check/spin at s==3 (normally instant in steady state)
                if (s == 2 && more && tid == 0)
                    fseen = __hip_atomic_fetch_add(in_flag, 0, __ATOMIC_RELAXED, __HIP_MEMORY_SCOPE_AGENT);
                if (s == 3 && more && tid == 0) {
                    while (fseen < c + 2) {
                        __builtin_amdgcn_s_sleep(2);
                        fseen = __hip_atomic_fetch_add(in_flag, 0, __ATOMIC_RELAXED, __HIP_MEMORY_SCOPE_AGENT);
                    }
                }
                // broadcast this wave's 32 new h values into uniform registers
#pragma unroll
                for (int k = 0; k < 32; k++) hs[k] = rdlane(hn_bc, k);
            }
            __syncthreads();   // aux complete before flush
            {   // chunk flush: coalesced write of CHUNK*128 floats
                float4 v = *reinterpret_cast<const float4*>(&aux[tid * 4]);
                *reinterpret_cast<float4*>(&seq_o[(size_t)t0 * HID + tid * 4]) = v;
            }
            __syncthreads();
            if (tid == 0)
                __hip_atomic_store(out_flag, c + 1, __ATOMIC_RELEASE, __HIP_MEMORY_SCOPE_AGENT);
            if (more) {   // rotate prefetched gi into place (static indexing)
#pragma unroll
                for (int u = 0; u < CHUNK; u++) {
                    g_r[u] = n_r[u]; g_z[u] = n_z[u]; g_n[u] = n_n[u];
                }
            }
        }
    } else {
        // ---------------- gi role: layer l (1..3) — R12-proven ----------------
        const float* W   = WihR + (size_t)(l - 1) * G3 * HID;
        const float* seq_in = ws + GI_TOT + (size_t)(l - 1) * T_SEQ * HID;
        float* gi_o      = ws + (size_t)l * T_SEQ * G3;
        int* in_flag     = &fl[(4 + (l - 1)) * 16];
        int* out_flag    = &fl[l * 16];

        float w[6][32];
        const float* wbase = W + q * 32;
#pragma unroll
        for (int i = 0; i < 6; i++) {
            const float4* wr = reinterpret_cast<const float4*>(wbase + (size_t)(row0 + i) * HID);
#pragma unroll
            for (int c = 0; c < 8; c++) {
                float4 v = wr[c];
                w[i][c * 4 + 0] = v.x; w[i][c * 4 + 1] = v.y;
                w[i][c * 4 + 2] = v.z; w[i][c * 4 + 3] = v.w;
            }
        }
        int m  = lane & 31;
        int m2 = tid & 31;
        int s2 = tid >> 5;
        const float* bb = bih + (size_t)l * G3;
        float br4[4], bz4[4], bn4[4];
#pragma unroll
        for (int u = 0; u < 4; u++) {
            int jj = u * 32 + m2;
            br4[u] = bb[jj]; bz4[u] = bb[HID + jj]; bn4[u] = bb[2 * HID + jj];
        }

        for (int c = 0; c < NCHUNK; c++) {
            if (tid == 0) {
                while (__hip_atomic_fetch_add(in_flag, 0, __ATOMIC_RELAXED, __HIP_MEMORY_SCOPE_AGENT) < c + 1)
                    __builtin_amdgcn_s_sleep(2);
            }
            __syncthreads();
            int t0 = c * CHUNK;
            float vseq[CHUNK];
            {
                const float* sp = seq_in + (size_t)t0 * HID + q * 32 + m;
#pragma unroll
                for (int s = 0; s < CHUNK; s++) vseq[s] = sp[s * HID];
            }
#pragma unroll
            for (int s = 0; s < CHUNK; s++) {
                float xs[32];
#pragma unroll
                for (int k = 0; k < 32; k++) xs[k] = rdlane(vseq[s], k);
                float acc[6];
#pragma unroll
                for (int i = 0; i < 6; i++) {
                    float a0 = 0.f, a1 = 0.f, a2 = 0.f, a3 = 0.f;
#pragma unroll
                    for (int k = 0; k < 32; k += 4) {
                        a0 += w[i][k]     * xs[k];
                        a1 += w[i][k + 1] * xs[k + 1];
                        a2 += w[i][k + 2] * xs[k + 2];
                        a3 += w[i][k + 3] * xs[k + 3];
                    }
                    acc[i] = (a0 + a1) + (a2 + a3);
                }
                float* pp = smem + s * 1536;
#pragma unroll
                for (int i = 0; i < 6; i += 2) {
                    float2 p; p.x = acc[i]; p.y = acc[i + 1];
                    *reinterpret_cast<float2*>(&pp[q * G3 + row0 + i]) = p;
                }
            }
            __syncthreads();   // the ONE barrier per chunk
#pragma unroll
            for (int u = 0; u < 4; u++) {
                int jj = u * 32 + m2;
                const float* pp = smem + s2 * 1536;
                float vr = (pp[jj]         + pp[G3 + jj])         + (pp[2*G3 + jj]         + pp[3*G3 + jj]);
                float vz = (pp[HID + jj]   + pp[G3 + HID + jj])   + (pp[2*G3 + HID + jj]   + pp[3*G3 + HID + jj]);
                float vn = (pp[2*HID + jj] + pp[G3 + 2*HID + jj]) + (pp[2*G3 + 2*HID + jj] + pp[3*G3 + 2*HID + jj]);
                float* gp = gi_o + (size_t)(t0 + s2) * G3;
                gp[jj]           = vr + br4[u];
                gp[HID + jj]     = vz + bz4[u];
                gp[2 * HID + jj] = vn + bn4[u];
            }
            __syncthreads();   // all gi stores drained before flag
            if (tid == 0)
                __hip_atomic_store(out_flag, c + 1, __ATOMIC_RELEASE, __HIP_MEMORY_SCOPE_AGENT);
        }
    }
}

// ---------------- FC head ----------------
__global__ void fc_kernel(const float* __restrict__ seq, const float* __restrict__ fc1w,
                          const float* __restrict__ fc1b, const float* __restrict__ fc2w,
                          const float* __restrict__ fc2b, float* __restrict__ out) {
    __shared__ float h3[HID];
    __shared__ float hid[HID];
    int t = blockIdx.x;
    int i = threadIdx.x;
    h3[i] = seq[t * HID + i];
    __syncthreads();
    const float4* w4 = reinterpret_cast<const float4*>(fc1w + i * HID);
    const float4* h4 = reinterpret_cast<const float4*>(h3);
    float a0 = 0.f, a1 = 0.f, a2 = 0.f, a3 = 0.f;
#pragma unroll
    for (int k = 0; k < 32; k += 4) {
        float4 w0 = w4[k], w1 = w4[k + 1], w2 = w4[k + 2], w3 = w4[k + 3];
        float4 h0 = h4[k], h1 = h4[k + 1], h2 = h4[k + 2], h3v = h4[k + 3];
        a0 += w0.x * h0.x + w0.y * h0.y + w0.z * h0.z + w0.w * h0.w;
        a1 += w1.x * h1.x + w1.y * h1.y + w1.z * h1.z + w1.w * h1.w;
        a2 += w2.x * h2.x + w2.y * h2.y + w2.z * h2.z + w2.w * h2.w;
        a3 += w3.x * h3v.x + w3.y * h3v.y + w3.z * h3v.z + w3.w * h3v.w;
    }
    float v = fc1b[i] + ((a0 + a1) + (a2 + a3));
    hid[i] = v > 0.0f ? v : 0.0f;
    __syncthreads();
    if (i < 3) {
        const float* w = fc2w + i * HID;
        float s = 0.f;
#pragma unroll
        for (int k = 0; k < HID; k++) s += w[k] * hid[k];
        out[t * 3 + i] = fc2b[i] + s;
    }
}

extern "C" void kernel_launch(void* const* d_in, const int* in_sizes, int n_in,
                              void* d_out, int out_size, void* d_ws, size_t ws_size,
                              hipStream_t stream) {
    const float* x     = (const float*)d_in[0];
    const float* Wih0  = (const float*)d_in[1];
    const float* WihR  = (const float*)d_in[2];   // (3, 384, 128)
    const float* Whh   = (const float*)d_in[3];   // (4, 384, 128)
    const float* bih   = (const float*)d_in[4];   // (4, 384)
    const float* bhh   = (const float*)d_in[5];   // (4, 384)
    const float* fc1w  = (const float*)d_in[6];
    const float* fc1b  = (const float*)d_in[7];
    const float* fc2w  = (const float*)d_in[8];
    const float* fc2b  = (const float*)d_in[9];
    float* out = (float*)d_out;
    float* ws  = (float*)d_ws;

    int*   flags = (int*)(ws + FLAG_OFF);
    float* gi0   = ws;
    float* seq3  = ws + GI_TOT + (size_t)3 * T_SEQ * HID;

    init_flags<<<1, 64, 0, stream>>>(flags);
    gi0_kernel<<<T_SEQ, G3, 0, stream>>>(x, Wih0, bih, gi0);
    pipe_kernel<<<7, 256, 0, stream>>>(ws, WihR, bih, Whh, bhh);
    fc_kernel<<<T_SEQ, HID, 0, stream>>>(seq3, fc1w, fc1b, fc2w, fc2b, out);
}

// Round 14
// 412.158 us; speedup vs baseline: 1.0625x; 1.0625x over previous
//
#include <hip/hip_runtime.h>
#include <math.h>

#define T_SEQ  512
#define HID    128
#define G3     384   // 3*HID, gate order r,z,n
#define NL     4
#define CHUNK  8
#define NCHUNK (T_SEQ / CHUNK)   // 64

// workspace layout (float offsets)
#define GI_TOT   (NL * T_SEQ * G3)
#define SEQ_TOT  (NL * T_SEQ * HID)
#define FLAG_OFF (GI_TOT + SEQ_TOT)

__device__ __forceinline__ float fsig(float x) {
    float e = __expf(-x);
    return 1.0f / (1.0f + e);
}
__device__ __forceinline__ float ftanh(float x) {
    float ax = fabsf(x);
    float e = __expf(-2.0f * ax);
    float t = (1.0f - e) / (1.0f + e);
    return copysignf(t, x);
}
// lane-register broadcast: VALU v_readlane_b32, stays off the DS pipe
__device__ __forceinline__ float rdlane(float v, int k) {
    return __uint_as_float(__builtin_amdgcn_readlane(__float_as_uint(v), k));
}

// Packed inner product (R10-proven): compiler -> v_pk_fma_f32.
#define PK_DOT16(S0, S1, W2, H2)                    \
    _Pragma("unroll")                               \
    for (int pc = 0; pc < 16; pc += 2) {            \
        S0 += W2[pc]     * H2[pc];                  \
        S1 += W2[pc + 1] * H2[pc + 1];              \
    }

// Handoff protocol (invalidate-free, stale-proof): writer = stores;
// __syncthreads (vmcnt drain -> L2); RELEASE agent flag store. Reader spins on
// RELAXED fetch_add(0) at the chunk head (RMW at coherence point: no buffer_inv,
// no stale line). R13 lesson: do NOT move polls/prefetches into the step loop --
// every __syncthreads drains vmcnt(0) for all waves, so in-loop global ops stall
// the next barrier by LLC latency. Chunk-granular staging at the head only.

// ---------------- init: reset handoff flags ----------------
__global__ void init_flags(int* fl) {
    int i = threadIdx.x;
    if (i < 8) fl[i * 16] = (i == 0) ? NCHUNK : 0;  // gi0 fully ready
}

// ---------------- layer-0 gi ----------------
__global__ void gi0_kernel(const float* __restrict__ x, const float* __restrict__ Wih0,
                           const float* __restrict__ bih, float* __restrict__ gi) {
    int t = blockIdx.x;
    int g = threadIdx.x;
    float x0 = x[t * 2048 + 1023];
    float x1 = x[t * 2048 + 1024 + 1023];
    gi[t * G3 + g] = bih[g] + Wih0[g * 2 + 0] * x0 + Wih0[g * 2 + 1] * x1;
}

// ---------------- persistent pipeline: 7 blocks x 256 threads ----------------
// bid 0,2,4,6 -> rec layer bid/2 ; bid 1,3,5 -> gi layer (bid+1)/2
// P1: wave q owns K-quarter; lane rg rows rg*6..+5; h held as wave-uniform
// float2 pairs written directly by v_readlane (no repack) -> v_pk_fma_f32.
// ps double-buffered -> ONE barrier/step. gi role: 8 independent steps,
// big ps, ONE barrier/chunk, distributed reduce (R12-proven).
__global__ __launch_bounds__(256, 1) void pipe_kernel(float* __restrict__ ws,
                                                      const float* __restrict__ WihR,
                                                      const float* __restrict__ bih,
                                                      const float* __restrict__ Whh,
                                                      const float* __restrict__ bhh) {
    __shared__ float smem[12288];  // gi: ps_big[8][4][384]; rec: psdb[2][1536] + aux@3072

    int bid  = blockIdx.x;
    int tid  = threadIdx.x;
    int lane = tid & 63;
    int q    = tid >> 6;         // wave = K-quarter
    int row0 = lane * 6;
    int* fl = (int*)(ws + FLAG_OFF);
    bool is_rec = (bid & 1) == 0;
    int  l      = is_rec ? (bid >> 1) : ((bid + 1) >> 1);

    if (is_rec) {
        // ---------------- rec role: layer l ----------------
        const float* W   = Whh + (size_t)l * G3 * HID;
        const float* gi  = ws + (size_t)l * T_SEQ * G3;
        float* seq_o     = ws + GI_TOT + (size_t)l * T_SEQ * HID;
        float* aux       = smem + 3072;            // [1024] chunk history
        int* in_flag     = &fl[l * 16];
        int* out_flag    = &fl[(4 + l) * 16];

        float w[6][32];
        const float* wbase = W + q * 32;
#pragma unroll
        for (int i = 0; i < 6; i++) {
            const float4* wr = reinterpret_cast<const float4*>(wbase + (size_t)(row0 + i) * HID);
#pragma unroll
            for (int c = 0; c < 8; c++) {
                float4 v = wr[c];
                w[i][c * 4 + 0] = v.x; w[i][c * 4 + 1] = v.y;
                w[i][c * 4 + 2] = v.z; w[i][c * 4 + 3] = v.w;
            }
        }

        int  m  = lane & 31;
        bool p2 = (lane < 32);
        int  j  = q * 32 + m;          // this wave's P2 output index
        const float* bb = bhh + (size_t)l * G3;
        float br = 0.f, bz = 0.f, bn = 0.f;
        if (p2) { br = bb[j]; bz = bb[HID + j]; bn = bb[2 * HID + j]; }

        float2 hs2[16];                // wave-uniform h slice, pair layout
#pragma unroll
        for (int k = 0; k < 16; k++) { hs2[k].x = 0.f; hs2[k].y = 0.f; }
        float hprev = 0.f;
        float g_r[CHUNK], g_z[CHUNK], g_n[CHUNK];

        for (int c = 0; c < NCHUNK; c++) {
            if (tid == 0) {
                while (__hip_atomic_fetch_add(in_flag, 0, __ATOMIC_RELAXED, __HIP_MEMORY_SCOPE_AGENT) < c + 1)
                    __builtin_amdgcn_s_sleep(2);
            }
            __syncthreads();
            int t0 = c * CHUNK;
            if (p2) {   // chunk-granular gi register stage (drained at first barrier)
                const float* gp = gi + (size_t)t0 * G3 + j;
#pragma unroll
                for (int s = 0; s < CHUNK; s++) {
                    g_r[s] = gp[s * G3];
                    g_z[s] = gp[s * G3 + HID];
                    g_n[s] = gp[s * G3 + 2 * HID];
                }
            }
#pragma unroll
            for (int s = 0; s < CHUNK; s++) {
                int t = t0 + s;
                float* psb = smem + (t & 1) * 1536;   // double-buffered partials
                // P1: packed matvec on wave-uniform hs2 (no LDS reads)
                float acc[6];
#pragma unroll
                for (int i = 0; i < 6; i++) {
                    const float2* w2 = reinterpret_cast<const float2*>(w[i]);
                    float2 s0 = {0.f, 0.f}, s1 = {0.f, 0.f};
                    PK_DOT16(s0, s1, w2, hs2);
                    acc[i] = (s0.x + s0.y) + (s1.x + s1.y);
                }
#pragma unroll
                for (int i = 0; i < 6; i += 2) {
                    float2 p; p.x = acc[i]; p.y = acc[i + 1];
                    *reinterpret_cast<float2*>(&psb[q * G3 + row0 + i]) = p;
                }
                __syncthreads();   // the ONLY barrier per step
                // P2 (replicated per wave, lanes 0..31): this wave's h slice
                float hn_bc = 0.f;
                if (p2) {
                    float ghr = (psb[j]         + psb[G3 + j])         + (psb[2*G3 + j]         + psb[3*G3 + j]);
                    float ghz = (psb[HID + j]   + psb[G3 + HID + j])   + (psb[2*G3 + HID + j]   + psb[3*G3 + HID + j]);
                    float ghn = (psb[2*HID + j] + psb[G3 + 2*HID + j]) + (psb[2*G3 + 2*HID + j] + psb[3*G3 + 2*HID + j]);
                    float r = fsig(g_r[s] + ghr + br);
                    float z = fsig(g_z[s] + ghz + bz);
                    float n = ftanh(g_n[s] + r * (ghn + bn));
                    float hn = (1.0f - z) * n + z * hprev;
                    hprev = hn;
                    aux[s * HID + j] = hn;
                    hn_bc = hn;
                }
                // broadcast: readlane writes pair components directly (no repack)
#pragma unroll
                for (int k = 0; k < 16; k++) {
                    hs2[k].x = rdlane(hn_bc, 2 * k);
                    hs2[k].y = rdlane(hn_bc, 2 * k + 1);
                }
            }
            __syncthreads();   // aux complete before flush
            {   // chunk flush: coalesced write of CHUNK*128 floats
                float4 v = *reinterpret_cast<const float4*>(&aux[tid * 4]);
                *reinterpret_cast<float4*>(&seq_o[(size_t)t0 * HID + tid * 4]) = v;
            }
            __syncthreads();
            if (tid == 0)
                __hip_atomic_store(out_flag, c + 1, __ATOMIC_RELEASE, __HIP_MEMORY_SCOPE_AGENT);
        }
    } else {
        // ---------------- gi role: layer l (1..3) — R12-proven ----------------
        const float* W   = WihR + (size_t)(l - 1) * G3 * HID;
        const float* seq_in = ws + GI_TOT + (size_t)(l - 1) * T_SEQ * HID;
        float* gi_o      = ws + (size_t)l * T_SEQ * G3;
        int* in_flag     = &fl[(4 + (l - 1)) * 16];
        int* out_flag    = &fl[l * 16];

        float w[6][32];
        const float* wbase = W + q * 32;
#pragma unroll
        for (int i = 0; i < 6; i++) {
            const float4* wr = reinterpret_cast<const float4*>(wbase + (size_t)(row0 + i) * HID);
#pragma unroll
            for (int c = 0; c < 8; c++) {
                float4 v = wr[c];
                w[i][c * 4 + 0] = v.x; w[i][c * 4 + 1] = v.y;
                w[i][c * 4 + 2] = v.z; w[i][c * 4 + 3] = v.w;
            }
        }
        int m  = lane & 31;
        int m2 = tid & 31;
        int s2 = tid >> 5;
        const float* bb = bih + (size_t)l * G3;
        float br4[4], bz4[4], bn4[4];
#pragma unroll
        for (int u = 0; u < 4; u++) {
            int jj = u * 32 + m2;
            br4[u] = bb[jj]; bz4[u] = bb[HID + jj]; bn4[u] = bb[2 * HID + jj];
        }

        for (int c = 0; c < NCHUNK; c++) {
            if (tid == 0) {
                while (__hip_atomic_fetch_add(in_flag, 0, __ATOMIC_RELAXED, __HIP_MEMORY_SCOPE_AGENT) < c + 1)
                    __builtin_amdgcn_s_sleep(2);
            }
            __syncthreads();
            int t0 = c * CHUNK;
            float vseq[CHUNK];
            {
                const float* sp = seq_in + (size_t)t0 * HID + q * 32 + m;
#pragma unroll
                for (int s = 0; s < CHUNK; s++) vseq[s] = sp[s * HID];
            }
#pragma unroll
            for (int s = 0; s < CHUNK; s++) {
                float xs[32];
#pragma unroll
                for (int k = 0; k < 32; k++) xs[k] = rdlane(vseq[s], k);
                float acc[6];
#pragma unroll
                for (int i = 0; i < 6; i++) {
                    float a0 = 0.f, a1 = 0.f, a2 = 0.f, a3 = 0.f;
#pragma unroll
                    for (int k = 0; k < 32; k += 4) {
                        a0 += w[i][k]     * xs[k];
                        a1 += w[i][k + 1] * xs[k + 1];
                        a2 += w[i][k + 2] * xs[k + 2];
                        a3 += w[i][k + 3] * xs[k + 3];
                    }
                    acc[i] = (a0 + a1) + (a2 + a3);
                }
                float* pp = smem + s * 1536;
#pragma unroll
                for (int i = 0; i < 6; i += 2) {
                    float2 p; p.x = acc[i]; p.y = acc[i + 1];
                    *reinterpret_cast<float2*>(&pp[q * G3 + row0 + i]) = p;
                }
            }
            __syncthreads();   // the ONE barrier per chunk
#pragma unroll
            for (int u = 0; u < 4; u++) {
                int jj = u * 32 + m2;
                const float* pp = smem + s2 * 1536;
                float vr = (pp[jj]         + pp[G3 + jj])         + (pp[2*G3 + jj]         + pp[3*G3 + jj]);
                float vz = (pp[HID + jj]   + pp[G3 + HID + jj])   + (pp[2*G3 + HID + jj]   + pp[3*G3 + HID + jj]);
                float vn = (pp[2*HID + jj] + pp[G3 + 2*HID + jj]) + (pp[2*G3 + 2*HID + jj] + pp[3*G3 + 2*HID + jj]);
                float* gp = gi_o + (size_t)(t0 + s2) * G3;
                gp[jj]           = vr + br4[u];
                gp[HID + jj]     = vz + bz4[u];
                gp[2 * HID + jj] = vn + bn4[u];
            }
            __syncthreads();   // all gi stores drained before flag
            if (tid == 0)
                __hip_atomic_store(out_flag, c + 1, __ATOMIC_RELEASE, __HIP_MEMORY_SCOPE_AGENT);
        }
    }
}

// ---------------- FC head ----------------
__global__ void fc_kernel(const float* __restrict__ seq, const float* __restrict__ fc1w,
                          const float* __restrict__ fc1b, const float* __restrict__ fc2w,
                          const float* __restrict__ fc2b, float* __restrict__ out) {
    __shared__ float h3[HID];
    __shared__ float hid[HID];
    int t = blockIdx.x;
    int i = threadIdx.x;
    h3[i] = seq[t * HID + i];
    __syncthreads();
    const float4* w4 = reinterpret_cast<const float4*>(fc1w + i * HID);
    const float4* h4 = reinterpret_cast<const float4*>(h3);
    float a0 = 0.f, a1 = 0.f, a2 = 0.f, a3 = 0.f;
#pragma unroll
    for (int k = 0; k < 32; k += 4) {
        float4 w0 = w4[k], w1 = w4[k + 1], w2 = w4[k + 2], w3 = w4[k + 3];
        float4 h0 = h4[k], h1 = h4[k + 1], h2 = h4[k + 2], h3v = h4[k + 3];
        a0 += w0.x * h0.x + w0.y * h0.y + w0.z * h0.z + w0.w * h0.w;
        a1 += w1.x * h1.x + w1.y * h1.y + w1.z * h1.z + w1.w * h1.w;
        a2 += w2.x * h2.x + w2.y * h2.y + w2.z * h2.z + w2.w * h2.w;
        a3 += w3.x * h3v.x + w3.y * h3v.y + w3.z * h3v.z + w3.w * h3v.w;
    }
    float v = fc1b[i] + ((a0 + a1) + (a2 + a3));
    hid[i] = v > 0.0f ? v : 0.0f;
    __syncthreads();
    if (i < 3) {
        const float* w = fc2w + i * HID;
        float s = 0.f;
#pragma unroll
        for (int k = 0; k < HID; k++) s += w[k] * hid[k];
        out[t * 3 + i] = fc2b[i] + s;
    }
}

extern "C" void kernel_launch(void* const* d_in, const int* in_sizes, int n_in,
                              void* d_out, int out_size, void* d_ws, size_t ws_size,
                              hipStream_t stream) {
    const float* x     = (const float*)d_in[0];
    const float* Wih0  = (const float*)d_in[1];
    const float* WihR  = (const float*)d_in[2];   // (3, 384, 128)
    const float* Whh   = (const float*)d_in[3];   // (4, 384, 128)
    const float* bih   = (const float*)d_in[4];   // (4, 384)
    const float* bhh   = (const float*)d_in[5];   // (4, 384)
    const float* fc1w  = (const float*)d_in[6];
    const float* fc1b  = (const float*)d_in[7];
    const float* fc2w  = (const float*)d_in[8];
    const float* fc2b  = (const float*)d_in[9];
    float* out = (float*)d_out;
    float* ws  = (float*)d_ws;

    int*   flags = (int*)(ws + FLAG_OFF);
    float* gi0   = ws;
    float* seq3  = ws + GI_TOT + (size_t)3 * T_SEQ * HID;

    init_flags<<<1, 64, 0, stream>>>(flags);
    gi0_kernel<<<T_SEQ, G3, 0, stream>>>(x, Wih0, bih, gi0);
    pipe_kernel<<<7, 256, 0, stream>>>(ws, WihR, bih, Whh, bhh);
    fc_kernel<<<T_SEQ, HID, 0, stream>>>(seq3, fc1w, fc1b, fc2w, fc2b, out);
}

// Round 15
// 388.277 us; speedup vs baseline: 1.1279x; 1.0615x over previous
//
#include <hip/hip_runtime.h>
#include <math.h>

#define T_SEQ  512
#define HID    128
#define G3     384   // 3*HID, gate order r,z,n
#define NL     4
#define CHUNK  8
#define NCHUNK (T_SEQ / CHUNK)   // 64

// workspace layout (float offsets)
#define GI_TOT   (NL * T_SEQ * G3)
#define SEQ_TOT  (NL * T_SEQ * HID)
#define FLAG_OFF (GI_TOT + SEQ_TOT)

__device__ __forceinline__ float fsig(float x) {
    float e = __expf(-x);
    return 1.0f / (1.0f + e);
}
__device__ __forceinline__ float ftanh(float x) {
    float ax = fabsf(x);
    float e = __expf(-2.0f * ax);
    float t = (1.0f - e) / (1.0f + e);
    return copysignf(t, x);
}
// lane-register broadcast: VALU v_readlane_b32, stays off the DS pipe
__device__ __forceinline__ float rdlane(float v, int k) {
    return __uint_as_float(__builtin_amdgcn_readlane(__float_as_uint(v), k));
}

// Handoff protocol (invalidate-free, stale-proof): writer = stores;
// __syncthreads (vmcnt drain -> L2); RELEASE agent flag store. Reader polls
// RELAXED fetch_add(0) (RMW at coherence point: no buffer_inv, no stale line).
// R15 refinement (tail-hoisted handshake): the poll RMW for the NEXT chunk is
// issued before the aux flush (latency hides under the flush drain), checked
// after it; next chunk's gi is register-staged at the chunk TAIL so its drain
// lands at the next chunk's step-0 barrier with P1 as cover. R13 lesson kept:
// nothing global inside the step loop.

// ---------------- init: reset handoff flags ----------------
__global__ void init_flags(int* fl) {
    int i = threadIdx.x;
    if (i < 8) fl[i * 16] = (i == 0) ? NCHUNK : 0;  // gi0 fully ready
}

// ---------------- layer-0 gi ----------------
__global__ void gi0_kernel(const float* __restrict__ x, const float* __restrict__ Wih0,
                           const float* __restrict__ bih, float* __restrict__ gi) {
    int t = blockIdx.x;
    int g = threadIdx.x;
    float x0 = x[t * 2048 + 1023];
    float x1 = x[t * 2048 + 1024 + 1023];
    gi[t * G3 + g] = bih[g] + Wih0[g * 2 + 0] * x0 + Wih0[g * 2 + 1] * x1;
}

// ---------------- persistent pipeline: 7 blocks x 256 threads ----------------
// bid 0,2,4,6 -> rec layer bid/2 ; bid 1,3,5 -> gi layer (bid+1)/2
// rec P1: wave q owns K-quarter; lane rg rows rg*6..+5; h wave-uniform regs
// (readlane broadcast). ps double-buffered -> ONE barrier/step (R12-proven).
// gi role: 8 independent steps, big ps, ONE barrier/chunk (R12-proven).
__global__ __launch_bounds__(256, 1) void pipe_kernel(float* __restrict__ ws,
                                                      const float* __restrict__ WihR,
                                                      const float* __restrict__ bih,
                                                      const float* __restrict__ Whh,
                                                      const float* __restrict__ bhh) {
    __shared__ float smem[12288];  // gi: ps_big[8][4][384]; rec: psdb[2][1536] + aux@3072

    int bid  = blockIdx.x;
    int tid  = threadIdx.x;
    int lane = tid & 63;
    int q    = tid >> 6;         // wave = K-quarter
    int row0 = lane * 6;
    int* fl = (int*)(ws + FLAG_OFF);
    bool is_rec = (bid & 1) == 0;
    int  l      = is_rec ? (bid >> 1) : ((bid + 1) >> 1);

    if (is_rec) {
        // ---------------- rec role: layer l ----------------
        const float* W   = Whh + (size_t)l * G3 * HID;
        const float* gi  = ws + (size_t)l * T_SEQ * G3;
        float* seq_o     = ws + GI_TOT + (size_t)l * T_SEQ * HID;
        float* aux       = smem + 3072;            // [1024] chunk history
        int* in_flag     = &fl[l * 16];
        int* out_flag    = &fl[(4 + l) * 16];

        float w[6][32];
        const float* wbase = W + q * 32;
#pragma unroll
        for (int i = 0; i < 6; i++) {
            const float4* wr = reinterpret_cast<const float4*>(wbase + (size_t)(row0 + i) * HID);
#pragma unroll
            for (int c = 0; c < 8; c++) {
                float4 v = wr[c];
                w[i][c * 4 + 0] = v.x; w[i][c * 4 + 1] = v.y;
                w[i][c * 4 + 2] = v.z; w[i][c * 4 + 3] = v.w;
            }
        }

        int  m  = lane & 31;
        bool p2 = (lane < 32);
        int  j  = q * 32 + m;          // this wave's P2 output index
        const float* bb = bhh + (size_t)l * G3;
        float br = 0.f, bz = 0.f, bn = 0.f;
        if (p2) { br = bb[j]; bz = bb[HID + j]; bn = bb[2 * HID + j]; }

        float hs[32];                  // wave-uniform h slice (this wave's K-quarter)
#pragma unroll
        for (int k = 0; k < 32; k++) hs[k] = 0.f;
        float hprev = 0.f;
        float g_r[CHUNK], g_z[CHUNK], g_n[CHUNK];
        int   fseen = 0;

        // prologue: wait chunk 0, stage its gi (drained at first step barrier)
        if (tid == 0) {
            while (__hip_atomic_fetch_add(in_flag, 0, __ATOMIC_RELAXED, __HIP_MEMORY_SCOPE_AGENT) < 1)
                __builtin_amdgcn_s_sleep(2);
        }
        __syncthreads();
        if (p2) {
            const float* gp = gi + j;
#pragma unroll
            for (int s = 0; s < CHUNK; s++) {
                g_r[s] = gp[s * G3];
                g_z[s] = gp[s * G3 + HID];
                g_n[s] = gp[s * G3 + 2 * HID];
            }
        }

        for (int c = 0; c < NCHUNK; c++) {
            int t0 = c * CHUNK;
            bool more = (c + 1 < NCHUNK);
#pragma unroll
            for (int s = 0; s < CHUNK; s++) {
                int t = t0 + s;
                float* psb = smem + (t & 1) * 1536;   // double-buffered partials
                // P1: matvec on wave-uniform hs (R12-proven form; no LDS reads)
                float acc[6];
#pragma unroll
                for (int i = 0; i < 6; i++) {
                    float a0 = 0.f, a1 = 0.f, a2 = 0.f, a3 = 0.f;
#pragma unroll
                    for (int k = 0; k < 32; k += 4) {
                        a0 += w[i][k]     * hs[k];
                        a1 += w[i][k + 1] * hs[k + 1];
                        a2 += w[i][k + 2] * hs[k + 2];
                        a3 += w[i][k + 3] * hs[k + 3];
                    }
                    acc[i] = (a0 + a1) + (a2 + a3);
                }
#pragma unroll
                for (int i = 0; i < 6; i += 2) {
                    float2 p; p.x = acc[i]; p.y = acc[i + 1];
                    *reinterpret_cast<float2*>(&psb[q * G3 + row0 + i]) = p;
                }
                __syncthreads();   // the ONLY barrier per step
                // P2 (replicated per wave, lanes 0..31): this wave's h slice
                float hn_bc = 0.f;
                if (p2) {
                    float ghr = (psb[j]         + psb[G3 + j])         + (psb[2*G3 + j]         + psb[3*G3 + j]);
                    float ghz = (psb[HID + j]   + psb[G3 + HID + j])   + (psb[2*G3 + HID + j]   + psb[3*G3 + HID + j]);
                    float ghn = (psb[2*HID + j] + psb[G3 + 2*HID + j]) + (psb[2*G3 + 2*HID + j] + psb[3*G3 + 2*HID + j]);
                    float r = fsig(g_r[s] + ghr + br);
                    float z = fsig(g_z[s] + ghz + bz);
                    float n = ftanh(g_n[s] + r * (ghn + bn));
                    float hn = (1.0f - z) * n + z * hprev;
                    hprev = hn;
                    aux[s * HID + j] = hn;
                    hn_bc = hn;
                }
                // broadcast this wave's 32 new h values into uniform registers
#pragma unroll
                for (int k = 0; k < 32; k++) hs[k] = rdlane(hn_bc, k);
            }
            __syncthreads();   // aux complete before flush
            // tail-hoisted handshake: issue next-chunk poll RMW; latency hides
            // under the flush stores + their drain at the next barrier.
            if (more && tid == 0)
                fseen = __hip_atomic_fetch_add(in_flag, 0, __ATOMIC_RELAXED, __HIP_MEMORY_SCOPE_AGENT);
            {   // chunk flush: coalesced write of CHUNK*128 floats
                float4 v = *reinterpret_cast<const float4*>(&aux[tid * 4]);
                *reinterpret_cast<float4*>(&seq_o[(size_t)t0 * HID + tid * 4]) = v;
            }
            __syncthreads();   // drains flush stores AND the poll RMW
            if (tid == 0)
                __hip_atomic_store(out_flag, c + 1, __ATOMIC_RELEASE, __HIP_MEMORY_SCOPE_AGENT);
            if (more && tid == 0) {   // steady state: already satisfied
                while (fseen < c + 2) {
                    __builtin_amdgcn_s_sleep(2);
                    fseen = __hip_atomic_fetch_add(in_flag, 0, __ATOMIC_RELAXED, __HIP_MEMORY_SCOPE_AGENT);
                }
            }
            __syncthreads();   // order tid0's spin before the stage below
            if (more && p2) {  // stage next chunk's gi at the TAIL; drains at
                               // next chunk's step-0 barrier with P1 as cover
                const float* gp = gi + (size_t)(t0 + CHUNK) * G3 + j;
#pragma unroll
                for (int s = 0; s < CHUNK; s++) {
                    g_r[s] = gp[s * G3];
                    g_z[s] = gp[s * G3 + HID];
                    g_n[s] = gp[s * G3 + 2 * HID];
                }
            }
        }
    } else {
        // ---------------- gi role: layer l (1..3) — R12-proven ----------------
        const float* W   = WihR + (size_t)(l - 1) * G3 * HID;
        const float* seq_in = ws + GI_TOT + (size_t)(l - 1) * T_SEQ * HID;
        float* gi_o      = ws + (size_t)l * T_SEQ * G3;
        int* in_flag     = &fl[(4 + (l - 1)) * 16];
        int* out_flag    = &fl[l * 16];

        float w[6][32];
        const float* wbase = W + q * 32;
#pragma unroll
        for (int i = 0; i < 6; i++) {
            const float4* wr = reinterpret_cast<const float4*>(wbase + (size_t)(row0 + i) * HID);
#pragma unroll
            for (int c = 0; c < 8; c++) {
                float4 v = wr[c];
                w[i][c * 4 + 0] = v.x; w[i][c * 4 + 1] = v.y;
                w[i][c * 4 + 2] = v.z; w[i][c * 4 + 3] = v.w;
            }
        }
        int m  = lane & 31;
        int m2 = tid & 31;
        int s2 = tid >> 5;
        const float* bb = bih + (size_t)l * G3;
        float br4[4], bz4[4], bn4[4];
#pragma unroll
        for (int u = 0; u < 4; u++) {
            int jj = u * 32 + m2;
            br4[u] = bb[jj]; bz4[u] = bb[HID + jj]; bn4[u] = bb[2 * HID + jj];
        }

        for (int c = 0; c < NCHUNK; c++) {
            if (tid == 0) {
                while (__hip_atomic_fetch_add(in_flag, 0, __ATOMIC_RELAXED, __HIP_MEMORY_SCOPE_AGENT) < c + 1)
                    __builtin_amdgcn_s_sleep(2);
            }
            __syncthreads();
            int t0 = c * CHUNK;
            float vseq[CHUNK];
            {
                const float* sp = seq_in + (size_t)t0 * HID + q * 32 + m;
#pragma unroll
                for (int s = 0; s < CHUNK; s++) vseq[s] = sp[s * HID];
            }
#pragma unroll
            for (int s = 0; s < CHUNK; s++) {
                float xs[32];
#pragma unroll
                for (int k = 0; k < 32; k++) xs[k] = rdlane(vseq[s], k);
                float acc[6];
#pragma unroll
                for (int i = 0; i < 6; i++) {
                    float a0 = 0.f, a1 = 0.f, a2 = 0.f, a3 = 0.f;
#pragma unroll
                    for (int k = 0; k < 32; k += 4) {
                        a0 += w[i][k]     * xs[k];
                        a1 += w[i][k + 1] * xs[k + 1];
                        a2 += w[i][k + 2] * xs[k + 2];
                        a3 += w[i][k + 3] * xs[k + 3];
                    }
                    acc[i] = (a0 + a1) + (a2 + a3);
                }
                float* pp = smem + s * 1536;
#pragma unroll
                for (int i = 0; i < 6; i += 2) {
                    float2 p; p.x = acc[i]; p.y = acc[i + 1];
                    *reinterpret_cast<float2*>(&pp[q * G3 + row0 + i]) = p;
                }
            }
            __syncthreads();   // the ONE barrier per chunk
#pragma unroll
            for (int u = 0; u < 4; u++) {
                int jj = u * 32 + m2;
                const float* pp = smem + s2 * 1536;
                float vr = (pp[jj]         + pp[G3 + jj])         + (pp[2*G3 + jj]         + pp[3*G3 + jj]);
                float vz = (pp[HID + jj]   + pp[G3 + HID + jj])   + (pp[2*G3 + HID + jj]   + pp[3*G3 + HID + jj]);
                float vn = (pp[2*HID + jj] + pp[G3 + 2*HID + jj]) + (pp[2*G3 + 2*HID + jj] + pp[3*G3 + 2*HID + jj]);
                float* gp = gi_o + (size_t)(t0 + s2) * G3;
                gp[jj]           = vr + br4[u];
                gp[HID + jj]     = vz + bz4[u];
                gp[2 * HID + jj] = vn + bn4[u];
            }
            __syncthreads();   // all gi stores drained before flag
            if (tid == 0)
                __hip_atomic_store(out_flag, c + 1, __ATOMIC_RELEASE, __HIP_MEMORY_SCOPE_AGENT);
        }
    }
}

// ---------------- FC head ----------------
__global__ void fc_kernel(const float* __restrict__ seq, const float* __restrict__ fc1w,
                          const float* __restrict__ fc1b, const float* __restrict__ fc2w,
                          const float* __restrict__ fc2b, float* __restrict__ out) {
    __shared__ float h3[HID];
    __shared__ float hid[HID];
    int t = blockIdx.x;
    int i = threadIdx.x;
    h3[i] = seq[t * HID + i];
    __syncthreads();
    const float4* w4 = reinterpret_cast<const float4*>(fc1w + i * HID);
    const float4* h4 = reinterpret_cast<const float4*>(h3);
    float a0 = 0.f, a1 = 0.f, a2 = 0.f, a3 = 0.f;
#pragma unroll
    for (int k = 0; k < 32; k += 4) {
        float4 w0 = w4[k], w1 = w4[k + 1], w2 = w4[k + 2], w3 = w4[k + 3];
        float4 h0 = h4[k], h1 = h4[k + 1], h2 = h4[k + 2], h3v = h4[k + 3];
        a0 += w0.x * h0.x + w0.y * h0.y + w0.z * h0.z + w0.w * h0.w;
        a1 += w1.x * h1.x + w1.y * h1.y + w1.z * h1.z + w1.w * h1.w;
        a2 += w2.x * h2.x + w2.y * h2.y + w2.z * h2.z + w2.w * h2.w;
        a3 += w3.x * h3v.x + w3.y * h3v.y + w3.z * h3v.z + w3.w * h3v.w;
    }
    float v = fc1b[i] + ((a0 + a1) + (a2 + a3));
    hid[i] = v > 0.0f ? v : 0.0f;
    __syncthreads();
    if (i < 3) {
        const float* w = fc2w + i * HID;
        float s = 0.f;
#pragma unroll
        for (int k = 0; k < HID; k++) s += w[k] * hid[k];
        out[t * 3 + i] = fc2b[i] + s;
    }
}

extern "C" void kernel_launch(void* const* d_in, const int* in_sizes, int n_in,
                              void* d_out, int out_size, void* d_ws, size_t ws_size,
                              hipStream_t stream) {
    const float* x     = (const float*)d_in[0];
    const float* Wih0  = (const float*)d_in[1];
    const float* WihR  = (const float*)d_in[2];   // (3, 384, 128)
    const float* Whh   = (const float*)d_in[3];   // (4, 384, 128)
    const float* bih   = (const float*)d_in[4];   // (4, 384)
    const float* bhh   = (const float*)d_in[5];   // (4, 384)
    const float* fc1w  = (const float*)d_in[6];
    const float* fc1b  = (const float*)d_in[7];
    const float* fc2w  = (const float*)d_in[8];
    const float* fc2b  = (const float*)d_in[9];
    float* out = (float*)d_out;
    float* ws  = (float*)d_ws;

    int*   flags = (int*)(ws + FLAG_OFF);
    float* gi0   = ws;
    float* seq3  = ws + GI_TOT + (size_t)3 * T_SEQ * HID;

    init_flags<<<1, 64, 0, stream>>>(flags);
    gi0_kernel<<<T_SEQ, G3, 0, stream>>>(x, Wih0, bih, gi0);
    pipe_kernel<<<7, 256, 0, stream>>>(ws, WihR, bih, Whh, bhh);
    fc_kernel<<<T_SEQ, HID, 0, stream>>>(seq3, fc1w, fc1b, fc2w, fc2b, out);
}